// Round 7
// baseline (87.245 us; speedup 1.0000x reference)
//
#include <hip/hip_runtime.h>
#include <math.h>

// Problem: N=8192, D=4096
//   inputs  (N, 2D) f32: mean = [:, :D], var = [:, D:]
//   targets (N, D)  f32
//   out = sum((mean - targets)^2 / var) + log(sum(var))   (scalar f32)
// Memory-bound: 384 MB read -> 1 float.
//
// R7: maximize memory-level parallelism. 8192 blocks x 256 threads ->
//     exactly 4 iterations/thread, fully unrolled: all 12 dwordx4 loads
//     hoist to the top (~70 VGPR -> ~28 waves/CU). Two-kernel reduction
//     (fused atomic finalize proven disastrous in R4/R5).

constexpr int N = 8192;
constexpr int D = 4096;
constexpr int BLOCKS = 8192;
constexpr int THREADS = 256;
constexpr int ITERS = 4;       // N*D/4 / (BLOCKS*THREADS) = 8,388,608 / 2,097,152

typedef float f32x4 __attribute__((ext_vector_type(4)));

__global__ __launch_bounds__(THREADS) void loss_partial_kernel(
    const float* __restrict__ inputs,
    const float* __restrict__ targets,
    float* __restrict__ partials)   // [2 * BLOCKS]: s1 then s2
{
    constexpr unsigned NTHREAD = (unsigned)BLOCKS * THREADS;  // 2,097,152

    float s1 = 0.0f;  // sum diff^2 / var
    float s2 = 0.0f;  // sum var

    const unsigned base = blockIdx.x * (unsigned)THREADS + threadIdx.x;

    f32x4 m[ITERS], v[ITERS], t[ITERS];
    #pragma unroll
    for (int it = 0; it < ITERS; ++it) {
        const unsigned i    = base + (unsigned)it * NTHREAD;
        const unsigned row  = i >> 10;           // D/4 = 1024 float4 per row
        const unsigned col4 = (i & 1023u) << 2;  // column in floats
        m[it] = *(const f32x4*)(inputs + (size_t)row * 8192u + col4);
        v[it] = *(const f32x4*)(inputs + (size_t)row * 8192u + 4096u + col4);
        t[it] = *(const f32x4*)(targets + (size_t)i * 4u);
    }

    #pragma unroll
    for (int it = 0; it < ITERS; ++it) {
        const float d0 = m[it].x - t[it].x;
        const float d1 = m[it].y - t[it].y;
        const float d2 = m[it].z - t[it].z;
        const float d3 = m[it].w - t[it].w;
        s1 += d0 * d0 * __builtin_amdgcn_rcpf(v[it].x);
        s1 += d1 * d1 * __builtin_amdgcn_rcpf(v[it].y);
        s1 += d2 * d2 * __builtin_amdgcn_rcpf(v[it].z);
        s1 += d3 * d3 * __builtin_amdgcn_rcpf(v[it].w);
        s2 += (v[it].x + v[it].y) + (v[it].z + v[it].w);
    }

    // wave (64-lane) shuffle reduction
    #pragma unroll
    for (int off = 32; off > 0; off >>= 1) {
        s1 += __shfl_down(s1, off, 64);
        s2 += __shfl_down(s2, off, 64);
    }

    __shared__ float l1[THREADS / 64];
    __shared__ float l2[THREADS / 64];
    const int wave = threadIdx.x >> 6;
    const int lane = threadIdx.x & 63;
    if (lane == 0) { l1[wave] = s1; l2[wave] = s2; }
    __syncthreads();

    if (threadIdx.x == 0) {
        const float a = (l1[0] + l1[1]) + (l1[2] + l1[3]);
        const float b = (l2[0] + l2[1]) + (l2[2] + l2[3]);
        partials[blockIdx.x]          = a;
        partials[BLOCKS + blockIdx.x] = b;
    }
}

__global__ __launch_bounds__(256) void loss_final_kernel(
    const float* __restrict__ partials,
    float* __restrict__ out)
{
    double s1 = 0.0, s2 = 0.0;
    for (int i = threadIdx.x; i < BLOCKS; i += 256) {
        s1 += (double)partials[i];
        s2 += (double)partials[BLOCKS + i];
    }

    #pragma unroll
    for (int off = 32; off > 0; off >>= 1) {
        s1 += __shfl_down(s1, off, 64);
        s2 += __shfl_down(s2, off, 64);
    }

    __shared__ double l1[4];
    __shared__ double l2[4];
    const int wave = threadIdx.x >> 6;
    const int lane = threadIdx.x & 63;
    if (lane == 0) { l1[wave] = s1; l2[wave] = s2; }
    __syncthreads();

    if (threadIdx.x == 0) {
        const double a = (l1[0] + l1[1]) + (l1[2] + l1[3]);
        const double b = (l2[0] + l2[1]) + (l2[2] + l2[3]);
        out[0] = (float)(a + log(b));
    }
}

extern "C" void kernel_launch(void* const* d_in, const int* in_sizes, int n_in,
                              void* d_out, int out_size, void* d_ws, size_t ws_size,
                              hipStream_t stream) {
    const float* inputs  = (const float*)d_in[0];
    const float* targets = (const float*)d_in[1];
    float* out      = (float*)d_out;
    float* partials = (float*)d_ws;   // 2 * BLOCKS * 4 = 64 KB

    loss_partial_kernel<<<BLOCKS, THREADS, 0, stream>>>(inputs, targets, partials);
    loss_final_kernel<<<1, 256, 0, stream>>>(partials, out);
}

// Round 8
// 80.517 us; speedup vs baseline: 1.0836x; 1.0836x over previous
//
#include <hip/hip_runtime.h>
#include <math.h>

// Problem: N=8192, D=4096
//   inputs  (N, 2D) f32: mean = [:, :D], var = [:, D:]
//   targets (N, D)  f32
//   out = sum((mean - targets)^2 / var) + log(sum(var))   (scalar f32)
// Memory-bound: 384 MB read -> 1 float.
//
// R8: all-resident grid (2048x256, exactly 8 blocks/CU) + explicit depth-2
//     software pipeline. __launch_bounds__(256,8) caps VGPR at 64 so all
//     2048 blocks are co-resident (single dispatch round — R7 showed multi-
//     round costs ~10us); prefetch registers force 6 dwordx4 loads in
//     flight per thread (R2 showed the clamp alone lets the compiler
//     serialize loads; R6 showed unclamped unroll-8 likely broke residency).

constexpr int N = 8192;
constexpr int D = 4096;
constexpr int BLOCKS = 2048;   // 256 CUs * 8 blocks/CU, all resident
constexpr int THREADS = 256;
constexpr int ITERS = 16;      // N*D/4 / (BLOCKS*THREADS)

typedef float f32x4 __attribute__((ext_vector_type(4)));

__global__ __launch_bounds__(THREADS, 8) void loss_partial_kernel(
    const float* __restrict__ inputs,
    const float* __restrict__ targets,
    float* __restrict__ partials)   // [2 * BLOCKS]: s1 then s2
{
    constexpr unsigned NTHREAD = (unsigned)BLOCKS * THREADS;  // 524,288

    float s1 = 0.0f;  // sum diff^2 / var
    float s2 = 0.0f;  // sum var

    unsigned i = blockIdx.x * (unsigned)THREADS + threadIdx.x;

    // prologue: load iteration 0
    unsigned row  = i >> 10;           // D/4 = 1024 float4 per row
    unsigned col4 = (i & 1023u) << 2;
    f32x4 m0 = *(const f32x4*)(inputs + (size_t)row * 8192u + col4);
    f32x4 v0 = *(const f32x4*)(inputs + (size_t)row * 8192u + 4096u + col4);
    f32x4 t0 = *(const f32x4*)(targets + (size_t)i * 4u);

    #pragma unroll 3
    for (int it = 0; it < ITERS - 1; ++it) {
        const unsigned i1 = i + NTHREAD;
        const unsigned row1  = i1 >> 10;
        const unsigned col41 = (i1 & 1023u) << 2;
        // issue next iteration's loads BEFORE consuming current ones:
        // consume then waits at vmcnt(3), keeping 3 loads in flight.
        const f32x4 m1 = *(const f32x4*)(inputs + (size_t)row1 * 8192u + col41);
        const f32x4 v1 = *(const f32x4*)(inputs + (size_t)row1 * 8192u + 4096u + col41);
        const f32x4 t1 = *(const f32x4*)(targets + (size_t)i1 * 4u);

        const float d0 = m0.x - t0.x;
        const float d1 = m0.y - t0.y;
        const float d2 = m0.z - t0.z;
        const float d3 = m0.w - t0.w;
        s1 += d0 * d0 * __builtin_amdgcn_rcpf(v0.x);
        s1 += d1 * d1 * __builtin_amdgcn_rcpf(v0.y);
        s1 += d2 * d2 * __builtin_amdgcn_rcpf(v0.z);
        s1 += d3 * d3 * __builtin_amdgcn_rcpf(v0.w);
        s2 += (v0.x + v0.y) + (v0.z + v0.w);

        m0 = m1; v0 = v1; t0 = t1; i = i1;
    }

    // epilogue: consume last
    {
        const float d0 = m0.x - t0.x;
        const float d1 = m0.y - t0.y;
        const float d2 = m0.z - t0.z;
        const float d3 = m0.w - t0.w;
        s1 += d0 * d0 * __builtin_amdgcn_rcpf(v0.x);
        s1 += d1 * d1 * __builtin_amdgcn_rcpf(v0.y);
        s1 += d2 * d2 * __builtin_amdgcn_rcpf(v0.z);
        s1 += d3 * d3 * __builtin_amdgcn_rcpf(v0.w);
        s2 += (v0.x + v0.y) + (v0.z + v0.w);
    }

    // wave (64-lane) shuffle reduction
    #pragma unroll
    for (int off = 32; off > 0; off >>= 1) {
        s1 += __shfl_down(s1, off, 64);
        s2 += __shfl_down(s2, off, 64);
    }

    __shared__ float l1[THREADS / 64];
    __shared__ float l2[THREADS / 64];
    const int wave = threadIdx.x >> 6;
    const int lane = threadIdx.x & 63;
    if (lane == 0) { l1[wave] = s1; l2[wave] = s2; }
    __syncthreads();

    if (threadIdx.x == 0) {
        const float a = (l1[0] + l1[1]) + (l1[2] + l1[3]);
        const float b = (l2[0] + l2[1]) + (l2[2] + l2[3]);
        partials[blockIdx.x]          = a;
        partials[BLOCKS + blockIdx.x] = b;
    }
}

__global__ __launch_bounds__(256) void loss_final_kernel(
    const float* __restrict__ partials,
    float* __restrict__ out)
{
    double s1 = 0.0, s2 = 0.0;
    for (int i = threadIdx.x; i < BLOCKS; i += 256) {
        s1 += (double)partials[i];
        s2 += (double)partials[BLOCKS + i];
    }

    #pragma unroll
    for (int off = 32; off > 0; off >>= 1) {
        s1 += __shfl_down(s1, off, 64);
        s2 += __shfl_down(s2, off, 64);
    }

    __shared__ double l1[4];
    __shared__ double l2[4];
    const int wave = threadIdx.x >> 6;
    const int lane = threadIdx.x & 63;
    if (lane == 0) { l1[wave] = s1; l2[wave] = s2; }
    __syncthreads();

    if (threadIdx.x == 0) {
        const double a = (l1[0] + l1[1]) + (l1[2] + l1[3]);
        const double b = (l2[0] + l2[1]) + (l2[2] + l2[3]);
        out[0] = (float)(a + log(b));
    }
}

extern "C" void kernel_launch(void* const* d_in, const int* in_sizes, int n_in,
                              void* d_out, int out_size, void* d_ws, size_t ws_size,
                              hipStream_t stream) {
    const float* inputs  = (const float*)d_in[0];
    const float* targets = (const float*)d_in[1];
    float* out      = (float*)d_out;
    float* partials = (float*)d_ws;   // 2 * BLOCKS * 4 = 16 KB

    loss_partial_kernel<<<BLOCKS, THREADS, 0, stream>>>(inputs, targets, partials);
    loss_final_kernel<<<1, 256, 0, stream>>>(partials, out);
}

// Round 9
// 79.854 us; speedup vs baseline: 1.0926x; 1.0083x over previous
//
#include <hip/hip_runtime.h>
#include <math.h>

// Problem: N=8192, D=4096
//   inputs  (N, 2D) f32: mean = [:, :D], var = [:, D:]
//   targets (N, D)  f32
//   out = sum((mean - targets)^2 / var) + log(sum(var))   (scalar f32)
// Memory-bound: 384 MB read -> 1 float.
//
// R9: block-LINEAR ownership (vs grid-stride). Block b owns triples
//     [b*4096,(b+1)*4096): its m+v loads jointly sweep a contiguous 128 KB
//     region of `inputs`, t loads a contiguous 64 KB of `targets` ->
//     sequential DRAM bursts instead of 8MB-stride row-thrash.
//     Phase-rotate iterations by (b&15) to de-camp channels.
//     Grid/unroll config = R6 (best so far, 77.3us): 2048x256, unroll 8.

constexpr int N = 8192;
constexpr int D = 4096;
constexpr int BLOCKS = 2048;   // 256 CUs * 8 blocks/CU, all resident
constexpr int THREADS = 256;
constexpr int ITERS = 16;      // 4096 triples per block / 256 threads

typedef float f32x4 __attribute__((ext_vector_type(4)));

__global__ __launch_bounds__(THREADS) void loss_partial_kernel(
    const float* __restrict__ inputs,
    const float* __restrict__ targets,
    float* __restrict__ partials)   // [2 * BLOCKS]: s1 then s2
{
    float s1 = 0.0f;  // sum diff^2 / var
    float s2 = 0.0f;  // sum var

    const unsigned b    = blockIdx.x;
    const unsigned base = b * (unsigned)(THREADS * ITERS) + threadIdx.x; // block-linear
    const unsigned ph   = b & 15u;   // per-block phase rotation (de-camp channels)

    #pragma unroll 8
    for (int it = 0; it < ITERS; ++it) {
        const unsigned it_eff = ((unsigned)it + ph) & 15u;
        const unsigned i      = base + it_eff * (unsigned)THREADS;
        const unsigned row    = i >> 10;           // D/4 = 1024 float4 per row
        const unsigned col4   = (i & 1023u) << 2;  // column in floats

        const f32x4 m = *(const f32x4*)(inputs + (size_t)row * 8192u + col4);
        const f32x4 v = *(const f32x4*)(inputs + (size_t)row * 8192u + 4096u + col4);
        const f32x4 t = *(const f32x4*)(targets + (size_t)i * 4u);

        const float d0 = m.x - t.x;
        const float d1 = m.y - t.y;
        const float d2 = m.z - t.z;
        const float d3 = m.w - t.w;

        s1 += d0 * d0 * __builtin_amdgcn_rcpf(v.x);
        s1 += d1 * d1 * __builtin_amdgcn_rcpf(v.y);
        s1 += d2 * d2 * __builtin_amdgcn_rcpf(v.z);
        s1 += d3 * d3 * __builtin_amdgcn_rcpf(v.w);
        s2 += (v.x + v.y) + (v.z + v.w);
    }

    // wave (64-lane) shuffle reduction
    #pragma unroll
    for (int off = 32; off > 0; off >>= 1) {
        s1 += __shfl_down(s1, off, 64);
        s2 += __shfl_down(s2, off, 64);
    }

    __shared__ float l1[THREADS / 64];
    __shared__ float l2[THREADS / 64];
    const int wave = threadIdx.x >> 6;
    const int lane = threadIdx.x & 63;
    if (lane == 0) { l1[wave] = s1; l2[wave] = s2; }
    __syncthreads();

    if (threadIdx.x == 0) {
        const float a = (l1[0] + l1[1]) + (l1[2] + l1[3]);
        const float b2 = (l2[0] + l2[1]) + (l2[2] + l2[3]);
        partials[blockIdx.x]          = a;
        partials[BLOCKS + blockIdx.x] = b2;
    }
}

__global__ __launch_bounds__(256) void loss_final_kernel(
    const float* __restrict__ partials,
    float* __restrict__ out)
{
    double s1 = 0.0, s2 = 0.0;
    for (int i = threadIdx.x; i < BLOCKS; i += 256) {
        s1 += (double)partials[i];
        s2 += (double)partials[BLOCKS + i];
    }

    #pragma unroll
    for (int off = 32; off > 0; off >>= 1) {
        s1 += __shfl_down(s1, off, 64);
        s2 += __shfl_down(s2, off, 64);
    }

    __shared__ double l1[4];
    __shared__ double l2[4];
    const int wave = threadIdx.x >> 6;
    const int lane = threadIdx.x & 63;
    if (lane == 0) { l1[wave] = s1; l2[wave] = s2; }
    __syncthreads();

    if (threadIdx.x == 0) {
        const double a = (l1[0] + l1[1]) + (l1[2] + l1[3]);
        const double b = (l2[0] + l2[1]) + (l2[2] + l2[3]);
        out[0] = (float)(a + log(b));
    }
}

extern "C" void kernel_launch(void* const* d_in, const int* in_sizes, int n_in,
                              void* d_out, int out_size, void* d_ws, size_t ws_size,
                              hipStream_t stream) {
    const float* inputs  = (const float*)d_in[0];
    const float* targets = (const float*)d_in[1];
    float* out      = (float*)d_out;
    float* partials = (float*)d_ws;   // 2 * BLOCKS * 4 = 16 KB

    loss_partial_kernel<<<BLOCKS, THREADS, 0, stream>>>(inputs, targets, partials);
    loss_final_kernel<<<1, 256, 0, stream>>>(partials, out);
}